// Round 9
// baseline (131.500 us; speedup 1.0000x reference)
//
#include <hip/hip_runtime.h>

// Problem constants: v (targets y), v_pred (queries x) are [4, 8192, 3] fp32.
#define BB 4
#define NN 8192
#define MM 8192
#define BN (BB * NN)

#define QB   128       // queries per block = 4 A-tiles (1 per wave pair)
#define BLK  512       // 8 waves: wave w -> A-tile w>>1, j-half w&1
#define NCH  8         // target chunks per block (full M = 8192)
#define TPC  1024      // targets per chunk
#define NT   32        // B-tiles per chunk image (32 KB)
#define NBLK ((NN / QB) * BB)   // 64 x 4 = 256 blocks = 1 per CU

typedef __bf16 bf16x8 __attribute__((ext_vector_type(8)));
typedef float  f32x16 __attribute__((ext_vector_type(16)));

// ws layout: part1[256] block partial sums (written by ALL blocks before the
// final kernel reads them -> kernel-boundary handoff, no poison sensitivity).
//
// v_mfma_f32_32x32x16_bf16 (layouts verified by R0/R2/R5/R8 absmax=0.0):
//   A: row=lane&31, k=(lane>>5)*8+e;  B: col=lane&31, k=(lane>>5)*8+e
//   D: col=lane&31, row=(r&3)+8*(r>>2)+4*(lane>>5)
// K-slot packing: k0..3 {2x0h,2x0h,2x0l,2x0l}x{y0h,y0l,y0h,y0l} = 2*x0*y0;
// k4..7 dim1; k8..11 dim2; k12,13 {-xx_h,-xx_l}x{1,1}; k14,15 {1,1}x{-yy_h,-yy_l}
// => with C=0: D = 2x.y - xx - yy = -d2.  min d2 = -max D.

static __device__ inline void split_bf(float v, __bf16& h, __bf16& l) {
    h = (__bf16)v;
    l = (__bf16)(v - (float)h);
}

static __device__ inline void packB(float y0, float y1, float y2,
                                    uint4& o0, uint4& o1) {
    __bf16 h0,l0,h1,l1,h2,l2,hy,ly;
    split_bf(y0, h0, l0);
    split_bf(y1, h1, l1);
    split_bf(y2, h2, l2);
    float nyy = -__builtin_fmaf(y2, y2, __builtin_fmaf(y1, y1, y0*y0));
    split_bf(nyy, hy, ly);
    const __bf16 one = (__bf16)1.0f;
    bf16x8 g0 = {h0,l0,h0,l0,h1,l1,h1,l1};
    bf16x8 g1 = {h2,l2,h2,l2,one,one,hy,ly};
    o0 = __builtin_bit_cast(uint4, g0);
    o1 = __builtin_bit_cast(uint4, g1);
}

__global__ __launch_bounds__(BLK, 2) void chamfer_full(
    const float* __restrict__ y,      // v      [B, M, 3] targets
    const float* __restrict__ x,      // v_pred [B, N, 3] queries
    float* __restrict__ part1)        // [NBLK] per-block partial sums
{
    __shared__ uint4 BIMG[2][NT * 64];   // 2 x 32 KB double-buffered B image
    __shared__ uint4 AIMG[4 * 64];       // 4 A-tiles, 4 KB
    __shared__ float red[2][QB];         // per-j-half per-query min d2
    __shared__ float ws8[8];

    const int t   = threadIdx.x;
    const int l   = t & 63;
    const int w   = t >> 6;          // wave 0..7
    const int hi  = l >> 5;          // frag part
    const int c32 = l & 31;
    const int at  = w >> 1;          // A-tile 0..3
    const int jh  = w & 1;           // j-half 0..1

    const float* yb = y + (size_t)blockIdx.y * MM * 3;

    // ---- prologue (once per block): A image + chunk-0 B image ----
    if (t < QB) {
        const float* xb = x + ((size_t)blockIdx.y * NN
                             + (size_t)blockIdx.x * QB) * 3;
        float x0 = xb[3*t+0], x1 = xb[3*t+1], x2 = xb[3*t+2];
        __bf16 h0,l0,h1,l1,h2,l2,hx,lx;
        split_bf(2.0f*x0, h0, l0);
        split_bf(2.0f*x1, h1, l1);
        split_bf(2.0f*x2, h2, l2);
        float nxx = -__builtin_fmaf(x2, x2, __builtin_fmaf(x1, x1, x0*x0));
        split_bf(nxx, hx, lx);
        const __bf16 one = (__bf16)1.0f;
        bf16x8 g0 = {h0,h0,l0,l0,h1,h1,l1,l1};
        bf16x8 g1 = {h2,h2,l2,l2,hx,lx,one,one};
        AIMG[(t>>5)*64 +      (t&31)] = __builtin_bit_cast(uint4, g0);
        AIMG[(t>>5)*64 + 32 + (t&31)] = __builtin_bit_cast(uint4, g1);
    }
    {
        float u0 = yb[3*t+0],       u1 = yb[3*t+1],       u2 = yb[3*t+2];
        float v0 = yb[3*(t+512)+0], v1 = yb[3*(t+512)+1], v2 = yb[3*(t+512)+2];
        uint4 o0,o1,o2,o3;
        packB(u0,u1,u2, o0,o1);
        packB(v0,v1,v2, o2,o3);
        BIMG[0][(t>>5)*64 +      (t&31)]       = o0;
        BIMG[0][(t>>5)*64 + 32 + (t&31)]       = o1;
        BIMG[0][((t+512)>>5)*64 +      (t&31)] = o2;
        BIMG[0][((t+512)>>5)*64 + 32 + (t&31)] = o3;
    }
    __syncthreads();
    const bf16x8 a0 = __builtin_bit_cast(bf16x8, AIMG[at*64 + hi*32 + c32]);

    // ---- main loop: 8 chunks, async-staged double buffer, 1 barrier/chunk ----
    f32x16 z;
#pragma unroll
    for (int r = 0; r < 16; ++r) z[r] = 0.0f;
    f32x16 best;
#pragma unroll
    for (int r = 0; r < 16; ++r) best[r] = -3.4e38f;

    int cur = 0;
#pragma unroll 1
    for (int c = 0; c < NCH; ++c) {
        // issue next-chunk staging loads BEFORE compute (latency hides under MFMA)
        float s0=0,s1=0,s2=0,s3=0,s4=0,s5=0;
        const bool more = (c + 1 < NCH);
        if (more) {
            const float* yn = yb + (size_t)(c+1) * TPC * 3;
            s0 = yn[3*t+0];       s1 = yn[3*t+1];       s2 = yn[3*t+2];
            s3 = yn[3*(t+512)+0]; s4 = yn[3*(t+512)+1]; s5 = yn[3*(t+512)+2];
        }
        // compute this wave's j-half: 16 j-tiles as 8 pairs, v_max3 fold
        const uint4* B = BIMG[cur];
        const int jb = jh * 16;
#pragma unroll
        for (int p2 = 0; p2 < 8; ++p2) {
            bf16x8 c0 = __builtin_bit_cast(bf16x8, B[(jb + 2*p2    )*64 + l]);
            bf16x8 c1 = __builtin_bit_cast(bf16x8, B[(jb + 2*p2 + 1)*64 + l]);
            f32x16 p = __builtin_amdgcn_mfma_f32_32x32x16_bf16(a0, c0, z, 0, 0, 0);
            f32x16 q = __builtin_amdgcn_mfma_f32_32x32x16_bf16(a0, c1, z, 0, 0, 0);
#pragma unroll
            for (int r = 0; r < 16; ++r)
                best[r] = fmaxf(fmaxf(best[r], p[r]), q[r]);   // v_max3_f32
        }
        if (more) {
            // pack staged values, write to the other buffer.
            // Safe without a pre-write barrier: all reads of BIMG[cur^1]
            // (chunk c-1) completed before chunk c-1's end barrier.
            uint4 o0,o1,o2,o3;
            packB(s0,s1,s2, o0,o1);
            packB(s3,s4,s5, o2,o3);
            uint4* Bn = BIMG[cur ^ 1];
            Bn[(t>>5)*64 +      (t&31)]       = o0;
            Bn[(t>>5)*64 + 32 + (t&31)]       = o1;
            Bn[((t+512)>>5)*64 +      (t&31)] = o2;
            Bn[((t+512)>>5)*64 + 32 + (t&31)] = o3;
            __syncthreads();
            cur ^= 1;
        }
    }

    // ---- epilogue: col-reduce, cross-j-half min, block sum, ONE store ----
#pragma unroll
    for (int r = 0; r < 16; ++r) {
        float v = best[r];
        v = fmaxf(v, __shfl_xor(v, 1, 64));
        v = fmaxf(v, __shfl_xor(v, 2, 64));
        v = fmaxf(v, __shfl_xor(v, 4, 64));
        v = fmaxf(v, __shfl_xor(v, 8, 64));
        v = fmaxf(v, __shfl_xor(v, 16, 64));
        if (c32 == 0) {
            const int row = (r & 3) + 8 * (r >> 2) + 4 * hi;
            red[jh][at * 32 + row] = -v;      // min d2 over this j-half
        }
    }
    __syncthreads();
    float m = (t < QB) ? fminf(red[0][t], red[1][t]) : 0.0f;
    for (int off = 32; off > 0; off >>= 1)
        m += __shfl_down(m, off, 64);
    if (l == 0) ws8[w] = m;
    __syncthreads();
    if (t == 0) {
        float s = 0.0f;
#pragma unroll
        for (int i = 0; i < 8; ++i) s += ws8[i];
        part1[blockIdx.y * (NN / QB) + blockIdx.x] = s;
    }
}

// Kernel 2: one block sums the 256 partials.
__global__ __launch_bounds__(256) void final_sum256(
    const float* __restrict__ part1,
    float* __restrict__ out)
{
    const int t = threadIdx.x;
    float v = part1[t];
    for (int off = 32; off > 0; off >>= 1)
        v += __shfl_down(v, off, 64);
    __shared__ float ws[4];
    if ((t & 63) == 0) ws[t >> 6] = v;
    __syncthreads();
    if (t == 0)
        out[0] = (ws[0] + ws[1] + ws[2] + ws[3]) * (1.0f / (float)BN);
}

extern "C" void kernel_launch(void* const* d_in, const int* in_sizes, int n_in,
                              void* d_out, int out_size, void* d_ws, size_t ws_size,
                              hipStream_t stream) {
    // setup_inputs order: d_in[0] = v (targets y), d_in[1] = v_pred (queries x)
    const float* v      = (const float*)d_in[0];
    const float* v_pred = (const float*)d_in[1];
    float* out = (float*)d_out;

    float* part1 = (float*)d_ws;     // 256 floats

    chamfer_full<<<dim3(NN / QB, BB), BLK, 0, stream>>>(v, v_pred, part1);
    final_sum256<<<1, 256, 0, stream>>>(part1, out);
}